// Round 15
// baseline (223.707 us; speedup 1.0000x reference)
//
#include <hip/hip_runtime.h>
#include <hip/hip_fp16.h>
#include <math.h>

#define NN 100000      // nodes
#define NE 3200000     // edges
#define INF 512        // in feat
#define HID 32         // hidden
#define NC 7           // classes
#define NBUK 391       // ceil(NN/256) node buckets of 256
#define CAP 16384      // fixed slots per bucket (mean 8184, sigma 90 -> unreachable)

typedef __attribute__((ext_vector_type(8))) _Float16 f16x8;
typedef __attribute__((ext_vector_type(4))) float    f32x4;

// ---------------- prep: zero bucket cursors + W1T[c][k] = fp16(W1[k][c]) ----------------
__global__ __launch_bounds__(256) void k_prep(const float* __restrict__ W1, _Float16* __restrict__ w1t,
                                              int* __restrict__ bcur){
    const int t = threadIdx.x, b = blockIdx.x;
    if (b == 0){
        if (t < NBUK) bcur[t] = 0;
        if (t + 256 < NBUK) bcur[t + 256] = 0;
    }
    for (int i = b*256 + t; i < INF*HID; i += 16*256){
        int k = i >> 5, c = i & 31;
        w1t[(size_t)c*INF + k] = (_Float16)W1[i];
    }
}

// ---------------- scatter v3: block-local counting sort -> coalesced slab writes ----------------
#define S_T 256
#define S_E 16
#define SB3 ((NE + S_T*S_E - 1)/(S_T*S_E))   // 782
__global__ __launch_bounds__(S_T) void k_scatter3(const void* __restrict__ edges,
                                                  int* __restrict__ bcur, int* __restrict__ ebuf){
    __shared__ int hist[NBUK];
    __shared__ int sc[512];            // scan workspace
    __shared__ int basep[NBUK+1];      // exclusive prefix within block
    __shared__ int gb[NBUK];           // reserved global slab base per bucket
    __shared__ int cur[NBUK];
    __shared__ int sorted[S_T*S_E];    // 16 KB block-sorted packed edges
    __shared__ int s_nz;
    const int tid = threadIdx.x;
    for (int i = tid; i < NBUK; i += S_T) hist[i] = 0;
    if (tid == 0) s_nz = 0;
    __syncthreads();
    if (((const unsigned*)edges)[2*tid + 1] != 0u) atomicOr(&s_nz, 1);
    __syncthreads();
    const bool f = (s_nz == 0);        // true -> int64 indices

    const int base_e = blockIdx.x * (S_T*S_E);
    const int nloc = min(S_T*S_E, NE - base_e);
    int val[S_E], bb[S_E];
    #pragma unroll
    for (int i = 0; i < S_E; ++i){
        int e = base_e + i*S_T + tid;
        bb[i] = -1;
        if (e < NE){
            int s, d;
            if (f){ s = (int)((const long long*)edges)[e]; d = (int)((const long long*)edges)[NE + e]; }
            else  { s = ((const int*)edges)[e];            d = ((const int*)edges)[NE + e]; }
            val[i] = (s << 8) | (d & 255);
            bb[i]  = d >> 8;
            atomicAdd(&hist[bb[i]], 1);
        }
    }
    __syncthreads();
    // block scan of hist (Hillis-Steele over 512, 2 elems/thread)
    sc[tid]       = (tid < NBUK)       ? hist[tid]       : 0;
    sc[tid + 256] = (tid + 256 < NBUK) ? hist[tid + 256] : 0;
    __syncthreads();
    for (int off = 1; off < 512; off <<= 1){
        int a0 = (tid >= off)        ? sc[tid - off]        : 0;
        int a1 = (tid + 256 >= off)  ? sc[tid + 256 - off]  : 0;
        __syncthreads();
        sc[tid] += a0; sc[tid + 256] += a1;
        __syncthreads();
    }
    if (tid < NBUK)       basep[tid]       = sc[tid] - hist[tid];
    if (tid + 256 < NBUK) basep[tid + 256] = sc[tid + 256] - hist[tid + 256];
    if (tid == 0) basep[NBUK] = nloc;
    __syncthreads();
    for (int i = tid; i < NBUK; i += S_T){
        cur[i] = basep[i];
        int c = hist[i];
        gb[i] = c ? (i*CAP + atomicAdd(&bcur[i], c)) : 0;
    }
    __syncthreads();
    // reorder into LDS (bucket-sorted within block)
    #pragma unroll
    for (int i = 0; i < S_E; ++i){
        if (bb[i] >= 0) sorted[atomicAdd(&cur[bb[i]], 1)] = val[i];
    }
    __syncthreads();
    // coalesced write-out: consecutive j -> consecutive slab addresses per bucket run
    for (int j = tid; j < nloc; j += S_T){
        int lo = 0, hi = NBUK;
        while (hi - lo > 1){ int mid = (lo + hi) >> 1; if (basep[mid] <= j) lo = mid; else hi = mid; }
        ebuf[gb[lo] + (j - basep[lo])] = sorted[j];
    }
}

// ---------------- GEMM1 (MFMA, LDS-free): h1s = fp16(x @ W1) unscaled ----------------
__global__ __launch_bounds__(512) void k_gemm1(const float* __restrict__ x, const _Float16* __restrict__ w1t,
                                               __half* __restrict__ h1s){
    const int tid  = threadIdx.x;
    const int lane = tid & 63;
    const int wid  = tid >> 6;            // wave 0..7
    const int mrow = lane & 15;
    const int kg   = lane >> 4;           // 0..3
    const int arow = blockIdx.x*128 + wid*16 + mrow;
    const bool rv  = arow < NN;
    const float* xrow = x + (size_t)arow*INF;
    const _Float16* wr0 = w1t + (size_t)mrow*INF;
    const _Float16* wr1 = w1t + (size_t)(16 + mrow)*INF;

    f32x4 acc0 = {0.f,0.f,0.f,0.f}, acc1 = {0.f,0.f,0.f,0.f};

    #pragma unroll 4
    for (int t = 0; t < INF/32; ++t){
        const int k0 = t*32 + kg*8;
        float4 a0 = make_float4(0.f,0.f,0.f,0.f), a1 = make_float4(0.f,0.f,0.f,0.f);
        if (rv){
            a0 = *(const float4*)&xrow[k0];
            a1 = *(const float4*)&xrow[k0 + 4];
        }
        f16x8 a;
        a[0]=(_Float16)a0.x; a[1]=(_Float16)a0.y; a[2]=(_Float16)a0.z; a[3]=(_Float16)a0.w;
        a[4]=(_Float16)a1.x; a[5]=(_Float16)a1.y; a[6]=(_Float16)a1.z; a[7]=(_Float16)a1.w;
        f16x8 b0 = *(const f16x8*)&wr0[k0];
        f16x8 b1 = *(const f16x8*)&wr1[k0];
        acc0 = __builtin_amdgcn_mfma_f32_16x16x32_f16(a, b0, acc0, 0, 0, 0);
        acc1 = __builtin_amdgcn_mfma_f32_16x16x32_f16(a, b1, acc1, 0, 0, 0);
    }

    const int rbase = blockIdx.x*128 + wid*16 + kg*4;
    #pragma unroll
    for (int j = 0; j < 4; ++j){
        int r = rbase + j;
        if (r < NN){
            h1s[(size_t)r*HID + mrow]      = __float2half(acc0[j]);
            h1s[(size_t)r*HID + 16 + mrow] = __float2half(acc1[j]);
        }
    }
}

// ---------------- per-bucket exact CSR + rbeg/rend + dinv + h1s row-scaling ----------------
__global__ __launch_bounds__(256) void k_csr(const int* __restrict__ bcur, const int* __restrict__ ebuf,
                                             int* __restrict__ rbeg, int* __restrict__ rend,
                                             int* __restrict__ csr, float* __restrict__ dinv,
                                             __half* __restrict__ h1s){
    __shared__ int cnt[256];
    __shared__ int sd[256];
    __shared__ int cur[256];
    const int b = blockIdx.x, t = threadIdx.x;
    const int beg = b*CAP, nE = bcur[b];
    cnt[t] = 0;
    __syncthreads();
    for (int i = t; i < nE; i += 256) atomicAdd(&cnt[ebuf[beg+i] & 255], 1);
    __syncthreads();
    int c = cnt[t];
    sd[t] = c;
    __syncthreads();
    for (int off = 1; off < 256; off <<= 1){
        int a = (t >= off) ? sd[t-off] : 0;
        __syncthreads();
        sd[t] += a;
        __syncthreads();
    }
    int ex = sd[t] - c;          // exclusive prefix within bucket
    cur[t] = ex;
    int v = b*256 + t;
    if (v < NN){
        float d = rsqrtf((float)(c + 1));     // +1 self-loop
        rbeg[v] = beg + ex;
        rend[v] = beg + ex + c;
        dinv[v] = d;
        __half2* hp = (__half2*)(h1s + (size_t)v*HID);   // fold dinv into h1s
        #pragma unroll
        for (int q = 0; q < 16; ++q){
            float2 tv = __half22float2(hp[q]);
            hp[q] = __floats2half2_rn(tv.x*d, tv.y*d);
        }
    }
    __syncthreads();
    for (int i = t; i < nE; i += 256){
        int e = ebuf[beg+i];
        int p = atomicAdd(&cur[e & 255], 1);
        csr[beg + p] = e >> 8;   // src node id
    }
}

// ---------------- Fused Aggregation1 + bias + ReLU + GEMM2 + dinv: h2s[NN][8] fp16 ----------------
__global__ __launch_bounds__(256) void k_agg1f(const __half* __restrict__ h1s, const int* __restrict__ rbeg,
                                               const int* __restrict__ rend, const int* __restrict__ csr,
                                               const float* __restrict__ dinv, const float* __restrict__ b1,
                                               const float* __restrict__ W2, __half* __restrict__ h2s){
    __shared__ float w2s[256];   // W2 padded [32][8]
    __shared__ float bs[32];
    {
        int t = threadIdx.x;
        w2s[t] = ((t & 7) < NC) ? W2[(t >> 3)*NC + (t & 7)] : 0.f;
        if (t < 32) bs[t] = b1[t];
    }
    __syncthreads();
    const int lane = threadIdx.x & 31;
    const int v = blockIdx.x*8 + (threadIdx.x >> 5);
    const int half16 = lane >> 4;    // edge slot 0/1
    const int fp = lane & 15;        // feature pair: feats 2fp, 2fp+1
    const __half2* h1v = (const __half2*)h1s;

    float2 a0 = {0.f,0.f}, a1 = {0.f,0.f}, a2 = {0.f,0.f}, a3 = {0.f,0.f};
    const int beg = rbeg[v], end = rend[v];
    int e = beg;
    for (; e + 16 <= end; e += 16){
        int s0 = csr[e      + half16];
        int s1 = csr[e +  2 + half16];
        int s2 = csr[e +  4 + half16];
        int s3 = csr[e +  6 + half16];
        int s4 = csr[e +  8 + half16];
        int s5 = csr[e + 10 + half16];
        int s6 = csr[e + 12 + half16];
        int s7 = csr[e + 14 + half16];
        float2 f0 = __half22float2(h1v[(size_t)s0*16 + fp]);
        float2 f1 = __half22float2(h1v[(size_t)s1*16 + fp]);
        float2 f2 = __half22float2(h1v[(size_t)s2*16 + fp]);
        float2 f3 = __half22float2(h1v[(size_t)s3*16 + fp]);
        float2 f4 = __half22float2(h1v[(size_t)s4*16 + fp]);
        float2 f5 = __half22float2(h1v[(size_t)s5*16 + fp]);
        float2 f6 = __half22float2(h1v[(size_t)s6*16 + fp]);
        float2 f7 = __half22float2(h1v[(size_t)s7*16 + fp]);
        a0.x += f0.x; a0.y += f0.y;  a1.x += f1.x; a1.y += f1.y;
        a2.x += f2.x; a2.y += f2.y;  a3.x += f3.x; a3.y += f3.y;
        a0.x += f4.x; a0.y += f4.y;  a1.x += f5.x; a1.y += f5.y;
        a2.x += f6.x; a2.y += f6.y;  a3.x += f7.x; a3.y += f7.y;
    }
    for (; e + 8 <= end; e += 8){
        int s0 = csr[e     + half16];
        int s1 = csr[e + 2 + half16];
        int s2 = csr[e + 4 + half16];
        int s3 = csr[e + 6 + half16];
        float2 f0 = __half22float2(h1v[(size_t)s0*16 + fp]);
        float2 f1 = __half22float2(h1v[(size_t)s1*16 + fp]);
        float2 f2 = __half22float2(h1v[(size_t)s2*16 + fp]);
        float2 f3 = __half22float2(h1v[(size_t)s3*16 + fp]);
        a0.x += f0.x; a0.y += f0.y;  a1.x += f1.x; a1.y += f1.y;
        a2.x += f2.x; a2.y += f2.y;  a3.x += f3.x; a3.y += f3.y;
    }
    for (; e + 2 <= end; e += 2){
        int s = csr[e + half16];
        float2 f = __half22float2(h1v[(size_t)s*16 + fp]);
        a0.x += f.x; a0.y += f.y;
    }
    if (e < end && half16 == 0){
        float2 f = __half22float2(h1v[(size_t)csr[e]*16 + fp]);
        a0.x += f.x; a0.y += f.y;
    }
    float tx = (a0.x + a1.x) + (a2.x + a3.x);
    float ty = (a0.y + a1.y) + (a2.y + a3.y);
    tx += __shfl_xor(tx, 16, 32);
    ty += __shfl_xor(ty, 16, 32);
    float2 self = __half22float2(h1v[(size_t)v*16 + fp]);
    float d = dinv[v];
    float rx = fmaxf(d*(tx + self.x) + bs[2*fp],     0.f);
    float ry = fmaxf(d*(ty + self.y) + bs[2*fp + 1], 0.f);
    float p[8];
    #pragma unroll
    for (int j = 0; j < 8; ++j)
        p[j] = fmaf(rx, w2s[(2*fp)*8 + j], ry * w2s[(2*fp + 1)*8 + j]);
    #pragma unroll
    for (int off = 8; off > 0; off >>= 1){
        #pragma unroll
        for (int j = 0; j < 8; ++j) p[j] += __shfl_xor(p[j], off, 16);
    }
    if (lane == 0){
        union { __half2 h[4]; float4 f; } u;
        u.h[0] = __floats2half2_rn(p[0]*d, p[1]*d);
        u.h[1] = __floats2half2_rn(p[2]*d, p[3]*d);
        u.h[2] = __floats2half2_rn(p[4]*d, p[5]*d);
        u.h[3] = __floats2half2_rn(p[6]*d, p[7]*d);
        *(float4*)&h2s[(size_t)v*8] = u.f;
    }
}

// ---------------- Aggregation 2: 32 lanes/node (4 edges x 8 feats), bias+softmax ----------------
__global__ __launch_bounds__(256) void k_agg2(const __half* __restrict__ h2s, const int* __restrict__ rbeg,
                                              const int* __restrict__ rend, const int* __restrict__ csr,
                                              const float* __restrict__ dinv, const float* __restrict__ b2,
                                              float* __restrict__ out){
    const int lane = threadIdx.x & 31;
    const int v = blockIdx.x*8 + (threadIdx.x >> 5);
    const int f = lane & 7, sub = lane >> 3;
    float acc = 0.f, acc2 = 0.f;
    const int beg = rbeg[v], end = rend[v];
    int e = beg + sub;
    for (; e + 4 < end; e += 8){
        int s0 = csr[e], s1 = csr[e+4];
        acc  += __half2float(h2s[(size_t)s0*8 + f]);
        acc2 += __half2float(h2s[(size_t)s1*8 + f]);
    }
    if (e < end) acc += __half2float(h2s[(size_t)csr[e]*8 + f]);
    acc += acc2;
    acc += __shfl_xor(acc, 8, 32);
    acc += __shfl_xor(acc, 16, 32);
    acc += __half2float(h2s[(size_t)v*8 + f]);   // self-loop term
    float logit = (f < NC) ? (dinv[v]*acc + b2[f]) : -INFINITY;
    float m = logit;
    #pragma unroll
    for (int off = 1; off < 8; off <<= 1) m = fmaxf(m, __shfl_xor(m, off, 8));
    float ex = __expf(logit - m);
    float s = ex;
    #pragma unroll
    for (int off = 1; off < 8; off <<= 1) s += __shfl_xor(s, off, 8);
    if (sub == 0 && f < NC) out[(size_t)v*NC + f] = ex / s;
}

extern "C" void kernel_launch(void* const* d_in, const int* in_sizes, int n_in,
                              void* d_out, int out_size, void* d_ws, size_t ws_size,
                              hipStream_t stream){
    const float* x  = (const float*)d_in[0];
    const void*  ei = d_in[1];
    const float* W1 = (const float*)d_in[2];
    const float* b1 = (const float*)d_in[3];
    const float* W2 = (const float*)d_in[4];
    const float* b2 = (const float*)d_in[5];
    float* out = (float*)d_out;

    char* ws = (char*)d_ws;
    size_t off = 0;
    auto alloc = [&](size_t bytes)->char*{
        char* p = ws + off; off += (bytes + 255) & ~(size_t)255; return p;
    };
    int*      ebuf = (int*)     alloc((size_t)NBUK*CAP*4);   // 25.6 MB slabs
    int*      csr  = (int*)     alloc((size_t)NBUK*CAP*4);   // 25.6 MB slabs
    int*      bcur = (int*)     alloc((size_t)NBUK*4);
    int*      rbeg = (int*)     alloc((size_t)NN*4);
    int*      rend = (int*)     alloc((size_t)NN*4);
    float*    dinv = (float*)   alloc((size_t)NN*4);
    _Float16* w1t  = (_Float16*)alloc((size_t)INF*HID*2);    // 32 KB fp16 W1^T
    __half*   h1s  = (__half*)  alloc((size_t)NN*HID*2);
    __half*   h2s  = (__half*)  alloc((size_t)NN*8*2);

    const int G1B = (NN + 127)/128;                 // 782

    k_prep    <<<16, 256, 0, stream>>>(W1, w1t, bcur);
    k_scatter3<<<SB3, S_T, 0, stream>>>(ei, bcur, ebuf);
    k_gemm1   <<<G1B, 512, 0, stream>>>(x, w1t, h1s);
    k_csr     <<<NBUK, 256, 0, stream>>>(bcur, ebuf, rbeg, rend, csr, dinv, h1s);
    k_agg1f   <<<NN/8, 256, 0, stream>>>(h1s, rbeg, rend, csr, dinv, b1, W2, h2s);
    k_agg2    <<<NN/8, 256, 0, stream>>>(h2s, rbeg, rend, csr, dinv, b2, out);
}

// Round 16
// 204.531 us; speedup vs baseline: 1.0938x; 1.0938x over previous
//
#include <hip/hip_runtime.h>
#include <hip/hip_fp16.h>
#include <math.h>

#define NN 100000      // nodes
#define NE 3200000     // edges
#define INF 512        // in feat
#define HID 32         // hidden
#define NC 7           // classes
#define NBUK 391       // ceil(NN/256) node buckets of 256
#define CAP 16384      // fixed slots per bucket (mean 8184, sigma 90 -> unreachable)

typedef __attribute__((ext_vector_type(8))) _Float16 f16x8;
typedef __attribute__((ext_vector_type(4))) float    f32x4;

// Per-block int64-vs-int32 detection: first 256 int64 slots' hi words all zero <=> int64.
#define DETECT_FLAG(edges, s_nz, f)                                            \
    if (threadIdx.x == 0) s_nz = 0;                                            \
    __syncthreads();                                                           \
    if (threadIdx.x < 256 && ((const unsigned*)(edges))[2*threadIdx.x + 1] != 0u) \
        atomicOr(&s_nz, 1);                                                    \
    __syncthreads();                                                           \
    const bool f = (s_nz == 0);

// ---------------- prep: zero bucket cursors + W1T[c][k] = fp16(W1[k][c]) ----------------
__global__ __launch_bounds__(256) void k_prep(const float* __restrict__ W1, _Float16* __restrict__ w1t,
                                              int* __restrict__ bcur){
    const int t = threadIdx.x, b = blockIdx.x;
    if (b == 0){
        if (t < NBUK) bcur[t] = 0;
        if (t + 256 < NBUK) bcur[t + 256] = 0;
    }
    for (int i = b*256 + t; i < INF*HID; i += 16*256){
        int k = i >> 5, c = i & 31;
        w1t[(size_t)c*INF + k] = (_Float16)W1[i];
    }
}

// ---------------- block-aggregated bucket scatter into fixed-capacity slabs ----------------
#define C_T 512
#define C_E 16
__global__ __launch_bounds__(C_T) void k_scatter(const void* __restrict__ edges,
                                                 int* __restrict__ bcur, int* __restrict__ ebuf){
    __shared__ int hist[NBUK];
    __shared__ int gbase[NBUK];
    __shared__ int s_nz;
    for (int i = threadIdx.x; i < NBUK; i += C_T) hist[i] = 0;
    DETECT_FLAG(edges, s_nz, f)
    const int base = blockIdx.x * (C_T * C_E);
    int val[C_E], bb[C_E], loc[C_E];
    #pragma unroll
    for (int i = 0; i < C_E; ++i){
        int e = base + i*C_T + threadIdx.x;
        bb[i] = -1;
        if (e < NE){
            int s, d;
            if (f){ s = (int)((const long long*)edges)[e]; d = (int)((const long long*)edges)[NE + e]; }
            else  { s = ((const int*)edges)[e];            d = ((const int*)edges)[NE + e]; }
            val[i] = (s << 8) | (d & 255);
            bb[i]  = d >> 8;
            loc[i] = atomicAdd(&hist[bb[i]], 1);
        }
    }
    __syncthreads();
    for (int i = threadIdx.x; i < NBUK; i += C_T){
        int c = hist[i];
        gbase[i] = c ? (i*CAP + atomicAdd(&bcur[i], c)) : 0;
    }
    __syncthreads();
    #pragma unroll
    for (int i = 0; i < C_E; ++i){
        if (bb[i] >= 0) ebuf[gbase[bb[i]] + loc[i]] = val[i];
    }
}

// ---------------- per-bucket exact CSR + rbeg/rend + dinv ----------------
__global__ __launch_bounds__(256) void k_csr(const int* __restrict__ bcur, const int* __restrict__ ebuf,
                                             int* __restrict__ rbeg, int* __restrict__ rend,
                                             int* __restrict__ csr, float* __restrict__ dinv){
    __shared__ int cnt[256];
    __shared__ int sd[256];
    __shared__ int cur[256];
    const int b = blockIdx.x, t = threadIdx.x;
    const int beg = b*CAP, nE = bcur[b];
    cnt[t] = 0;
    __syncthreads();
    for (int i = t; i < nE; i += 256) atomicAdd(&cnt[ebuf[beg+i] & 255], 1);
    __syncthreads();
    int c = cnt[t];
    sd[t] = c;
    __syncthreads();
    for (int off = 1; off < 256; off <<= 1){
        int a = (t >= off) ? sd[t-off] : 0;
        __syncthreads();
        sd[t] += a;
        __syncthreads();
    }
    int ex = sd[t] - c;          // exclusive prefix within bucket
    cur[t] = ex;
    int v = b*256 + t;
    if (v < NN){
        rbeg[v] = beg + ex;
        rend[v] = beg + ex + c;
        dinv[v] = rsqrtf((float)(c + 1));     // +1 self-loop
    }
    __syncthreads();
    for (int i = t; i < nE; i += 256){
        int e = ebuf[beg+i];
        int p = atomicAdd(&cur[e & 255], 1);
        csr[beg + p] = e >> 8;   // src node id
    }
}

// ---------------- GEMM1 (MFMA, LDS-free): h1s = fp16((x @ W1) * dinv[row]) ----------------
// 64-row blocks, 256 threads, NO LDS -> occupancy capped by VGPR only (~8 blocks/CU).
// B-fragments straight from 32 KB L2-resident W1T.
__global__ __launch_bounds__(256) void k_gemm1(const float* __restrict__ x, const _Float16* __restrict__ w1t,
                                               const float* __restrict__ dinv, __half* __restrict__ h1s){
    const int tid  = threadIdx.x;
    const int lane = tid & 63;
    const int wid  = tid >> 6;            // wave 0..3
    const int mrow = lane & 15;
    const int kg   = lane >> 4;           // 0..3
    const int arow = blockIdx.x*64 + wid*16 + mrow;
    const bool rv  = arow < NN;
    const float* xrow = x + (size_t)arow*INF;
    const _Float16* wr0 = w1t + (size_t)mrow*INF;
    const _Float16* wr1 = w1t + (size_t)(16 + mrow)*INF;

    f32x4 acc0 = {0.f,0.f,0.f,0.f}, acc1 = {0.f,0.f,0.f,0.f};

    #pragma unroll 4
    for (int t = 0; t < INF/32; ++t){
        const int k0 = t*32 + kg*8;
        float4 a0 = make_float4(0.f,0.f,0.f,0.f), a1 = make_float4(0.f,0.f,0.f,0.f);
        if (rv){
            a0 = *(const float4*)&xrow[k0];
            a1 = *(const float4*)&xrow[k0 + 4];
        }
        f16x8 a;
        a[0]=(_Float16)a0.x; a[1]=(_Float16)a0.y; a[2]=(_Float16)a0.z; a[3]=(_Float16)a0.w;
        a[4]=(_Float16)a1.x; a[5]=(_Float16)a1.y; a[6]=(_Float16)a1.z; a[7]=(_Float16)a1.w;
        f16x8 b0 = *(const f16x8*)&wr0[k0];
        f16x8 b1 = *(const f16x8*)&wr1[k0];
        acc0 = __builtin_amdgcn_mfma_f32_16x16x32_f16(a, b0, acc0, 0, 0, 0);
        acc1 = __builtin_amdgcn_mfma_f32_16x16x32_f16(a, b1, acc1, 0, 0, 0);
    }

    const int rbase = blockIdx.x*64 + wid*16 + kg*4;
    #pragma unroll
    for (int j = 0; j < 4; ++j){
        int r = rbase + j;
        if (r < NN){
            float d = dinv[r];
            h1s[(size_t)r*HID + mrow]      = __float2half(acc0[j]*d);
            h1s[(size_t)r*HID + 16 + mrow] = __float2half(acc1[j]*d);
        }
    }
}

// ---------------- Fused Aggregation1 + bias + ReLU + GEMM2 + dinv: h2s[NN][8] fp16 ----------------
__global__ __launch_bounds__(256) void k_agg1f(const __half* __restrict__ h1s, const int* __restrict__ rbeg,
                                               const int* __restrict__ rend, const int* __restrict__ csr,
                                               const float* __restrict__ dinv, const float* __restrict__ b1,
                                               const float* __restrict__ W2, __half* __restrict__ h2s){
    __shared__ float w2s[256];   // W2 padded [32][8]
    __shared__ float bs[32];
    {
        int t = threadIdx.x;
        w2s[t] = ((t & 7) < NC) ? W2[(t >> 3)*NC + (t & 7)] : 0.f;
        if (t < 32) bs[t] = b1[t];
    }
    __syncthreads();
    const int lane = threadIdx.x & 31;
    const int v = blockIdx.x*8 + (threadIdx.x >> 5);
    const int half16 = lane >> 4;    // edge slot 0/1
    const int fp = lane & 15;        // feature pair: feats 2fp, 2fp+1
    const __half2* h1v = (const __half2*)h1s;

    float2 a0 = {0.f,0.f}, a1 = {0.f,0.f}, a2 = {0.f,0.f}, a3 = {0.f,0.f};
    const int beg = rbeg[v], end = rend[v];
    int e = beg;
    for (; e + 16 <= end; e += 16){
        int s0 = csr[e      + half16];
        int s1 = csr[e +  2 + half16];
        int s2 = csr[e +  4 + half16];
        int s3 = csr[e +  6 + half16];
        int s4 = csr[e +  8 + half16];
        int s5 = csr[e + 10 + half16];
        int s6 = csr[e + 12 + half16];
        int s7 = csr[e + 14 + half16];
        float2 f0 = __half22float2(h1v[(size_t)s0*16 + fp]);
        float2 f1 = __half22float2(h1v[(size_t)s1*16 + fp]);
        float2 f2 = __half22float2(h1v[(size_t)s2*16 + fp]);
        float2 f3 = __half22float2(h1v[(size_t)s3*16 + fp]);
        float2 f4 = __half22float2(h1v[(size_t)s4*16 + fp]);
        float2 f5 = __half22float2(h1v[(size_t)s5*16 + fp]);
        float2 f6 = __half22float2(h1v[(size_t)s6*16 + fp]);
        float2 f7 = __half22float2(h1v[(size_t)s7*16 + fp]);
        a0.x += f0.x; a0.y += f0.y;  a1.x += f1.x; a1.y += f1.y;
        a2.x += f2.x; a2.y += f2.y;  a3.x += f3.x; a3.y += f3.y;
        a0.x += f4.x; a0.y += f4.y;  a1.x += f5.x; a1.y += f5.y;
        a2.x += f6.x; a2.y += f6.y;  a3.x += f7.x; a3.y += f7.y;
    }
    for (; e + 8 <= end; e += 8){
        int s0 = csr[e     + half16];
        int s1 = csr[e + 2 + half16];
        int s2 = csr[e + 4 + half16];
        int s3 = csr[e + 6 + half16];
        float2 f0 = __half22float2(h1v[(size_t)s0*16 + fp]);
        float2 f1 = __half22float2(h1v[(size_t)s1*16 + fp]);
        float2 f2 = __half22float2(h1v[(size_t)s2*16 + fp]);
        float2 f3 = __half22float2(h1v[(size_t)s3*16 + fp]);
        a0.x += f0.x; a0.y += f0.y;  a1.x += f1.x; a1.y += f1.y;
        a2.x += f2.x; a2.y += f2.y;  a3.x += f3.x; a3.y += f3.y;
    }
    for (; e + 2 <= end; e += 2){
        int s = csr[e + half16];
        float2 f = __half22float2(h1v[(size_t)s*16 + fp]);
        a0.x += f.x; a0.y += f.y;
    }
    if (e < end && half16 == 0){
        float2 f = __half22float2(h1v[(size_t)csr[e]*16 + fp]);
        a0.x += f.x; a0.y += f.y;
    }
    float tx = (a0.x + a1.x) + (a2.x + a3.x);
    float ty = (a0.y + a1.y) + (a2.y + a3.y);
    tx += __shfl_xor(tx, 16, 32);
    ty += __shfl_xor(ty, 16, 32);
    float2 self = __half22float2(h1v[(size_t)v*16 + fp]);
    float d = dinv[v];
    float rx = fmaxf(d*(tx + self.x) + bs[2*fp],     0.f);
    float ry = fmaxf(d*(ty + self.y) + bs[2*fp + 1], 0.f);
    float p[8];
    #pragma unroll
    for (int j = 0; j < 8; ++j)
        p[j] = fmaf(rx, w2s[(2*fp)*8 + j], ry * w2s[(2*fp + 1)*8 + j]);
    #pragma unroll
    for (int off = 8; off > 0; off >>= 1){
        #pragma unroll
        for (int j = 0; j < 8; ++j) p[j] += __shfl_xor(p[j], off, 16);
    }
    if (lane == 0){
        union { __half2 h[4]; float4 f; } u;
        u.h[0] = __floats2half2_rn(p[0]*d, p[1]*d);
        u.h[1] = __floats2half2_rn(p[2]*d, p[3]*d);
        u.h[2] = __floats2half2_rn(p[4]*d, p[5]*d);
        u.h[3] = __floats2half2_rn(p[6]*d, p[7]*d);
        *(float4*)&h2s[(size_t)v*8] = u.f;
    }
}

// ---------------- Aggregation 2: 32 lanes/node (4 edges x 8 feats), bias+softmax ----------------
__global__ __launch_bounds__(256) void k_agg2(const __half* __restrict__ h2s, const int* __restrict__ rbeg,
                                              const int* __restrict__ rend, const int* __restrict__ csr,
                                              const float* __restrict__ dinv, const float* __restrict__ b2,
                                              float* __restrict__ out){
    const int lane = threadIdx.x & 31;
    const int v = blockIdx.x*8 + (threadIdx.x >> 5);
    const int f = lane & 7, sub = lane >> 3;
    float acc = 0.f, acc2 = 0.f;
    const int beg = rbeg[v], end = rend[v];
    int e = beg + sub;
    for (; e + 4 < end; e += 8){
        int s0 = csr[e], s1 = csr[e+4];
        acc  += __half2float(h2s[(size_t)s0*8 + f]);
        acc2 += __half2float(h2s[(size_t)s1*8 + f]);
    }
    if (e < end) acc += __half2float(h2s[(size_t)csr[e]*8 + f]);
    acc += acc2;
    acc += __shfl_xor(acc, 8, 32);
    acc += __shfl_xor(acc, 16, 32);
    acc += __half2float(h2s[(size_t)v*8 + f]);   // self-loop term
    float logit = (f < NC) ? (dinv[v]*acc + b2[f]) : -INFINITY;
    float m = logit;
    #pragma unroll
    for (int off = 1; off < 8; off <<= 1) m = fmaxf(m, __shfl_xor(m, off, 8));
    float ex = __expf(logit - m);
    float s = ex;
    #pragma unroll
    for (int off = 1; off < 8; off <<= 1) s += __shfl_xor(s, off, 8);
    if (sub == 0 && f < NC) out[(size_t)v*NC + f] = ex / s;
}

extern "C" void kernel_launch(void* const* d_in, const int* in_sizes, int n_in,
                              void* d_out, int out_size, void* d_ws, size_t ws_size,
                              hipStream_t stream){
    const float* x  = (const float*)d_in[0];
    const void*  ei = d_in[1];
    const float* W1 = (const float*)d_in[2];
    const float* b1 = (const float*)d_in[3];
    const float* W2 = (const float*)d_in[4];
    const float* b2 = (const float*)d_in[5];
    float* out = (float*)d_out;

    char* ws = (char*)d_ws;
    size_t off = 0;
    auto alloc = [&](size_t bytes)->char*{
        char* p = ws + off; off += (bytes + 255) & ~(size_t)255; return p;
    };
    int*      ebuf = (int*)     alloc((size_t)NBUK*CAP*4);   // 25.6 MB slabs
    int*      csr  = (int*)     alloc((size_t)NBUK*CAP*4);   // 25.6 MB slabs
    int*      bcur = (int*)     alloc((size_t)NBUK*4);
    int*      rbeg = (int*)     alloc((size_t)NN*4);
    int*      rend = (int*)     alloc((size_t)NN*4);
    float*    dinv = (float*)   alloc((size_t)NN*4);
    _Float16* w1t  = (_Float16*)alloc((size_t)INF*HID*2);    // 32 KB fp16 W1^T
    __half*   h1s  = (__half*)  alloc((size_t)NN*HID*2);
    __half*   h2s  = (__half*)  alloc((size_t)NN*8*2);

    const int G1B = (NN + 63)/64;                   // 1563
    const int SB  = (NE + C_T*C_E - 1)/(C_T*C_E);   // 391

    k_prep   <<<16, 256, 0, stream>>>(W1, w1t, bcur);
    k_scatter<<<SB, C_T, 0, stream>>>(ei, bcur, ebuf);
    k_csr    <<<NBUK, 256, 0, stream>>>(bcur, ebuf, rbeg, rend, csr, dinv);
    k_gemm1  <<<G1B, 256, 0, stream>>>(x, w1t, dinv, h1s);
    k_agg1f  <<<NN/8, 256, 0, stream>>>(h1s, rbeg, rend, csr, dinv, b1, W2, h2s);
    k_agg2   <<<NN/8, 256, 0, stream>>>(h2s, rbeg, rend, csr, dinv, b2, out);
}

// Round 17
// 193.561 us; speedup vs baseline: 1.1557x; 1.0567x over previous
//
#include <hip/hip_runtime.h>
#include <hip/hip_fp16.h>
#include <math.h>

#define NN 100000      // nodes
#define NE 3200000     // edges
#define INF 512        // in feat
#define HID 32         // hidden
#define NC 7           // classes
#define NBUK 391       // ceil(NN/256) node buckets of 256
#define CAP 16384      // fixed slots per bucket (mean 8184, sigma 90 -> unreachable)

typedef __attribute__((ext_vector_type(8))) _Float16 f16x8;
typedef __attribute__((ext_vector_type(4))) float    f32x4;

// Per-block int64-vs-int32 detection: first 256 int64 slots' hi words all zero <=> int64.
#define DETECT_FLAG(edges, s_nz, f)                                            \
    if (threadIdx.x == 0) s_nz = 0;                                            \
    __syncthreads();                                                           \
    if (threadIdx.x < 256 && ((const unsigned*)(edges))[2*threadIdx.x + 1] != 0u) \
        atomicOr(&s_nz, 1);                                                    \
    __syncthreads();                                                           \
    const bool f = (s_nz == 0);

// ---------------- zero the bucket cursors ----------------
__global__ void k_zero(int* __restrict__ bcur){
    if (threadIdx.x < NBUK) bcur[threadIdx.x] = 0;
}

// ---------------- scatter v4: loc[] rank + scan + LDS reorder -> bucket-run coalesced writes ------
#define C_T 512
#define C_E 16
__global__ __launch_bounds__(C_T) void k_scatter4(const void* __restrict__ edges,
                                                  int* __restrict__ bcur, int* __restrict__ ebuf){
    __shared__ int hist[NBUK];
    __shared__ int basep[NBUK];        // block-local exclusive prefix
    __shared__ int gb[NBUK];           // reserved global slab base
    __shared__ int sc[C_T];            // scan workspace
    __shared__ int sorted[C_T*C_E];    // 32 KB bucket-sorted packed edges
    __shared__ int s_nz;
    const int tid = threadIdx.x;
    for (int i = tid; i < NBUK; i += C_T) hist[i] = 0;
    DETECT_FLAG(edges, s_nz, f)

    const int base = blockIdx.x * (C_T * C_E);
    int val[C_E], bb[C_E], loc[C_E];
    #pragma unroll
    for (int i = 0; i < C_E; ++i){
        int e = base + i*C_T + tid;
        bb[i] = -1;
        if (e < NE){
            int s, d;
            if (f){ s = (int)((const long long*)edges)[e]; d = (int)((const long long*)edges)[NE + e]; }
            else  { s = ((const int*)edges)[e];            d = ((const int*)edges)[NE + e]; }
            val[i] = (s << 8) | (d & 255);
            bb[i]  = d >> 8;
            loc[i] = atomicAdd(&hist[bb[i]], 1);    // within-bucket rank, reused below
        }
    }
    __syncthreads();
    // 512-wide Hillis-Steele scan of hist (1 elem/thread, NBUK=391<512)
    int h0 = (tid < NBUK) ? hist[tid] : 0;
    sc[tid] = h0;
    __syncthreads();
    for (int off = 1; off < C_T; off <<= 1){
        int a = (tid >= off) ? sc[tid - off] : 0;
        __syncthreads();
        sc[tid] += a;
        __syncthreads();
    }
    if (tid < NBUK){
        basep[tid] = sc[tid] - h0;
        gb[tid] = h0 ? (tid*CAP + atomicAdd(&bcur[tid], h0)) : 0;
    }
    __syncthreads();
    // reorder into LDS using the pass-1 rank (no second atomic pass)
    #pragma unroll
    for (int i = 0; i < C_E; ++i){
        if (bb[i] >= 0) sorted[basep[bb[i]] + loc[i]] = val[i];
    }
    __syncthreads();
    // bucket-run coalesced write-out: wave w handles buckets w, w+8, ...
    const int wid = tid >> 6, lane = tid & 63;
    for (int b = wid; b < NBUK; b += 8){
        const int n = hist[b], bp = basep[b], g = gb[b];
        for (int j = lane; j < n; j += 64)
            ebuf[g + j] = sorted[bp + j];
    }
}

// ---------------- per-bucket exact CSR + rbeg/rend + dinv ----------------
__global__ __launch_bounds__(256) void k_csr(const int* __restrict__ bcur, const int* __restrict__ ebuf,
                                             int* __restrict__ rbeg, int* __restrict__ rend,
                                             int* __restrict__ csr, float* __restrict__ dinv){
    __shared__ int cnt[256];
    __shared__ int sd[256];
    __shared__ int cur[256];
    const int b = blockIdx.x, t = threadIdx.x;
    const int beg = b*CAP, nE = bcur[b];
    cnt[t] = 0;
    __syncthreads();
    for (int i = t; i < nE; i += 256) atomicAdd(&cnt[ebuf[beg+i] & 255], 1);
    __syncthreads();
    int c = cnt[t];
    sd[t] = c;
    __syncthreads();
    for (int off = 1; off < 256; off <<= 1){
        int a = (t >= off) ? sd[t-off] : 0;
        __syncthreads();
        sd[t] += a;
        __syncthreads();
    }
    int ex = sd[t] - c;          // exclusive prefix within bucket
    cur[t] = ex;
    int v = b*256 + t;
    if (v < NN){
        rbeg[v] = beg + ex;
        rend[v] = beg + ex + c;
        dinv[v] = rsqrtf((float)(c + 1));     // +1 self-loop
    }
    __syncthreads();
    for (int i = t; i < nE; i += 256){
        int e = ebuf[beg+i];
        int p = atomicAdd(&cur[e & 255], 1);
        csr[beg + p] = e >> 8;   // src node id
    }
}

// ---------------- GEMM1 (MFMA): h1s = fp16((x @ W1) * dinv[row]), [NN][32] ----------------
// R10's proven version: 64-row blocks, 4 waves, W1 staged fp16 transposed in LDS (WSTR 520).
#define WSTR 520
__global__ __launch_bounds__(256) void k_gemm1(const float* __restrict__ x, const float* __restrict__ W1,
                                               const float* __restrict__ dinv, __half* __restrict__ h1s){
    __shared__ _Float16 wt[32*WSTR];   // 33.3 KB
    const int tid = threadIdx.x;
    for (int i = tid; i < INF*HID; i += 256){
        int k = i >> 5, c = i & 31;
        wt[c*WSTR + k] = (_Float16)W1[i];
    }
    __syncthreads();

    const int lane = tid & 63;
    const int wid  = tid >> 6;            // wave 0..3
    const int mrow = lane & 15;
    const int kg   = lane >> 4;           // 0..3
    const int arow = blockIdx.x*64 + wid*16 + mrow;
    const bool rv  = arow < NN;
    const float* xrow = x + (size_t)arow*INF;
    const _Float16* wt0 = wt + mrow*WSTR;
    const _Float16* wt1 = wt + (16 + mrow)*WSTR;

    f32x4 acc0 = {0.f,0.f,0.f,0.f}, acc1 = {0.f,0.f,0.f,0.f};

    #pragma unroll 4
    for (int t = 0; t < INF/32; ++t){
        const int k0 = t*32 + kg*8;
        float4 a0 = make_float4(0.f,0.f,0.f,0.f), a1 = make_float4(0.f,0.f,0.f,0.f);
        if (rv){
            a0 = *(const float4*)&xrow[k0];
            a1 = *(const float4*)&xrow[k0 + 4];
        }
        f16x8 a;
        a[0]=(_Float16)a0.x; a[1]=(_Float16)a0.y; a[2]=(_Float16)a0.z; a[3]=(_Float16)a0.w;
        a[4]=(_Float16)a1.x; a[5]=(_Float16)a1.y; a[6]=(_Float16)a1.z; a[7]=(_Float16)a1.w;
        f16x8 b0 = *(const f16x8*)&wt0[k0];
        f16x8 b1 = *(const f16x8*)&wt1[k0];
        acc0 = __builtin_amdgcn_mfma_f32_16x16x32_f16(a, b0, acc0, 0, 0, 0);
        acc1 = __builtin_amdgcn_mfma_f32_16x16x32_f16(a, b1, acc1, 0, 0, 0);
    }

    const int rbase = blockIdx.x*64 + wid*16 + kg*4;
    #pragma unroll
    for (int j = 0; j < 4; ++j){
        int r = rbase + j;
        if (r < NN){
            float d = dinv[r];
            h1s[(size_t)r*HID + mrow]      = __float2half(acc0[j]*d);
            h1s[(size_t)r*HID + 16 + mrow] = __float2half(acc1[j]*d);
        }
    }
}

// ---------------- Fused Aggregation1 + bias + ReLU + GEMM2 + dinv: h2s[NN][8] fp16 ----------------
__global__ __launch_bounds__(256) void k_agg1f(const __half* __restrict__ h1s, const int* __restrict__ rbeg,
                                               const int* __restrict__ rend, const int* __restrict__ csr,
                                               const float* __restrict__ dinv, const float* __restrict__ b1,
                                               const float* __restrict__ W2, __half* __restrict__ h2s){
    __shared__ float w2s[256];   // W2 padded [32][8]
    __shared__ float bs[32];
    {
        int t = threadIdx.x;
        w2s[t] = ((t & 7) < NC) ? W2[(t >> 3)*NC + (t & 7)] : 0.f;
        if (t < 32) bs[t] = b1[t];
    }
    __syncthreads();
    const int lane = threadIdx.x & 31;
    const int v = blockIdx.x*8 + (threadIdx.x >> 5);
    const int half16 = lane >> 4;    // edge slot 0/1
    const int fp = lane & 15;        // feature pair: feats 2fp, 2fp+1
    const __half2* h1v = (const __half2*)h1s;

    float2 a0 = {0.f,0.f}, a1 = {0.f,0.f}, a2 = {0.f,0.f}, a3 = {0.f,0.f};
    const int beg = rbeg[v], end = rend[v];
    int e = beg;
    for (; e + 16 <= end; e += 16){
        int s0 = csr[e      + half16];
        int s1 = csr[e +  2 + half16];
        int s2 = csr[e +  4 + half16];
        int s3 = csr[e +  6 + half16];
        int s4 = csr[e +  8 + half16];
        int s5 = csr[e + 10 + half16];
        int s6 = csr[e + 12 + half16];
        int s7 = csr[e + 14 + half16];
        float2 f0 = __half22float2(h1v[(size_t)s0*16 + fp]);
        float2 f1 = __half22float2(h1v[(size_t)s1*16 + fp]);
        float2 f2 = __half22float2(h1v[(size_t)s2*16 + fp]);
        float2 f3 = __half22float2(h1v[(size_t)s3*16 + fp]);
        float2 f4 = __half22float2(h1v[(size_t)s4*16 + fp]);
        float2 f5 = __half22float2(h1v[(size_t)s5*16 + fp]);
        float2 f6 = __half22float2(h1v[(size_t)s6*16 + fp]);
        float2 f7 = __half22float2(h1v[(size_t)s7*16 + fp]);
        a0.x += f0.x; a0.y += f0.y;  a1.x += f1.x; a1.y += f1.y;
        a2.x += f2.x; a2.y += f2.y;  a3.x += f3.x; a3.y += f3.y;
        a0.x += f4.x; a0.y += f4.y;  a1.x += f5.x; a1.y += f5.y;
        a2.x += f6.x; a2.y += f6.y;  a3.x += f7.x; a3.y += f7.y;
    }
    for (; e + 8 <= end; e += 8){
        int s0 = csr[e     + half16];
        int s1 = csr[e + 2 + half16];
        int s2 = csr[e + 4 + half16];
        int s3 = csr[e + 6 + half16];
        float2 f0 = __half22float2(h1v[(size_t)s0*16 + fp]);
        float2 f1 = __half22float2(h1v[(size_t)s1*16 + fp]);
        float2 f2 = __half22float2(h1v[(size_t)s2*16 + fp]);
        float2 f3 = __half22float2(h1v[(size_t)s3*16 + fp]);
        a0.x += f0.x; a0.y += f0.y;  a1.x += f1.x; a1.y += f1.y;
        a2.x += f2.x; a2.y += f2.y;  a3.x += f3.x; a3.y += f3.y;
    }
    for (; e + 2 <= end; e += 2){
        int s = csr[e + half16];
        float2 f = __half22float2(h1v[(size_t)s*16 + fp]);
        a0.x += f.x; a0.y += f.y;
    }
    if (e < end && half16 == 0){
        float2 f = __half22float2(h1v[(size_t)csr[e]*16 + fp]);
        a0.x += f.x; a0.y += f.y;
    }
    float tx = (a0.x + a1.x) + (a2.x + a3.x);
    float ty = (a0.y + a1.y) + (a2.y + a3.y);
    tx += __shfl_xor(tx, 16, 32);
    ty += __shfl_xor(ty, 16, 32);
    float2 self = __half22float2(h1v[(size_t)v*16 + fp]);
    float d = dinv[v];
    float rx = fmaxf(d*(tx + self.x) + bs[2*fp],     0.f);
    float ry = fmaxf(d*(ty + self.y) + bs[2*fp + 1], 0.f);
    float p[8];
    #pragma unroll
    for (int j = 0; j < 8; ++j)
        p[j] = fmaf(rx, w2s[(2*fp)*8 + j], ry * w2s[(2*fp + 1)*8 + j]);
    #pragma unroll
    for (int off = 8; off > 0; off >>= 1){
        #pragma unroll
        for (int j = 0; j < 8; ++j) p[j] += __shfl_xor(p[j], off, 16);
    }
    if (lane == 0){
        union { __half2 h[4]; float4 f; } u;
        u.h[0] = __floats2half2_rn(p[0]*d, p[1]*d);
        u.h[1] = __floats2half2_rn(p[2]*d, p[3]*d);
        u.h[2] = __floats2half2_rn(p[4]*d, p[5]*d);
        u.h[3] = __floats2half2_rn(p[6]*d, p[7]*d);
        *(float4*)&h2s[(size_t)v*8] = u.f;
    }
}

// ---------------- Aggregation 2: 32 lanes/node (4 edges x 8 feats), bias+softmax ----------------
__global__ __launch_bounds__(256) void k_agg2(const __half* __restrict__ h2s, const int* __restrict__ rbeg,
                                              const int* __restrict__ rend, const int* __restrict__ csr,
                                              const float* __restrict__ dinv, const float* __restrict__ b2,
                                              float* __restrict__ out){
    const int lane = threadIdx.x & 31;
    const int v = blockIdx.x*8 + (threadIdx.x >> 5);
    const int f = lane & 7, sub = lane >> 3;
    float acc = 0.f, acc2 = 0.f;
    const int beg = rbeg[v], end = rend[v];
    int e = beg + sub;
    for (; e + 4 < end; e += 8){
        int s0 = csr[e], s1 = csr[e+4];
        acc  += __half2float(h2s[(size_t)s0*8 + f]);
        acc2 += __half2float(h2s[(size_t)s1*8 + f]);
    }
    if (e < end) acc += __half2float(h2s[(size_t)csr[e]*8 + f]);
    acc += acc2;
    acc += __shfl_xor(acc, 8, 32);
    acc += __shfl_xor(acc, 16, 32);
    acc += __half2float(h2s[(size_t)v*8 + f]);   // self-loop term
    float logit = (f < NC) ? (dinv[v]*acc + b2[f]) : -INFINITY;
    float m = logit;
    #pragma unroll
    for (int off = 1; off < 8; off <<= 1) m = fmaxf(m, __shfl_xor(m, off, 8));
    float ex = __expf(logit - m);
    float s = ex;
    #pragma unroll
    for (int off = 1; off < 8; off <<= 1) s += __shfl_xor(s, off, 8);
    if (sub == 0 && f < NC) out[(size_t)v*NC + f] = ex / s;
}

extern "C" void kernel_launch(void* const* d_in, const int* in_sizes, int n_in,
                              void* d_out, int out_size, void* d_ws, size_t ws_size,
                              hipStream_t stream){
    const float* x  = (const float*)d_in[0];
    const void*  ei = d_in[1];
    const float* W1 = (const float*)d_in[2];
    const float* b1 = (const float*)d_in[3];
    const float* W2 = (const float*)d_in[4];
    const float* b2 = (const float*)d_in[5];
    float* out = (float*)d_out;

    char* ws = (char*)d_ws;
    size_t off = 0;
    auto alloc = [&](size_t bytes)->char*{
        char* p = ws + off; off += (bytes + 255) & ~(size_t)255; return p;
    };
    int*    ebuf = (int*)   alloc((size_t)NBUK*CAP*4);   // 25.6 MB slabs
    int*    csr  = (int*)   alloc((size_t)NBUK*CAP*4);   // 25.6 MB slabs
    int*    bcur = (int*)   alloc((size_t)NBUK*4);
    int*    rbeg = (int*)   alloc((size_t)NN*4);
    int*    rend = (int*)   alloc((size_t)NN*4);
    float*  dinv = (float*) alloc((size_t)NN*4);
    __half* h1s  = (__half*)alloc((size_t)NN*HID*2);
    __half* h2s  = (__half*)alloc((size_t)NN*8*2);

    const int G1B = (NN + 63)/64;                   // 1563
    const int SB  = (NE + C_T*C_E - 1)/(C_T*C_E);   // 391

    k_zero    <<<1, 512, 0, stream>>>(bcur);
    k_scatter4<<<SB, C_T, 0, stream>>>(ei, bcur, ebuf);
    k_csr     <<<NBUK, 256, 0, stream>>>(bcur, ebuf, rbeg, rend, csr, dinv);
    k_gemm1   <<<G1B, 256, 0, stream>>>(x, W1, dinv, h1s);
    k_agg1f   <<<NN/8, 256, 0, stream>>>(h1s, rbeg, rend, csr, dinv, b1, W2, h2s);
    k_agg2    <<<NN/8, 256, 0, stream>>>(h2s, rbeg, rend, csr, dinv, b2, out);
}